// Round 23
// baseline (124.883 us; speedup 1.0000x reference)
//
#include <hip/hip_runtime.h>
#include <hip/hip_fp16.h>

#define LL 16384
#define HH 128
#define WW 128
#define CC 64
#define NH 8
#define EPSF 1e-7f
#define KVCHUNKS 32

typedef __attribute__((ext_vector_type(8))) _Float16 f16x8;
typedef __attribute__((ext_vector_type(4))) float f32x4;
typedef __attribute__((ext_vector_type(8))) unsigned short u16x8;

static __device__ __forceinline__ unsigned short f2h_bits(float v) {
    const _Float16 h = (_Float16)v;
    unsigned short b;
    __builtin_memcpy(&b, &h, 2);
    return b;
}
static __device__ __forceinline__ float h2f_u16(unsigned short s) {
    _Float16 h;
    __builtin_memcpy(&h, &s, 2);
    return (float)h;
}
static __device__ __forceinline__ float h2f_lo(unsigned int u) {
    return h2f_u16((unsigned short)(u & 0xffffu));
}
static __device__ __forceinline__ float h2f_hi(unsigned int u) {
    return h2f_u16((unsigned short)(u >> 16));
}

// ---------------- Kernel P0: zero KV/KS + conv wprep + qkv wprep (no deps) ----------
// blocks 0-80: zero KV+KS (20736 floats); 81-336: conv wfrag; 337-432: qkv wqkvf.
__global__ void prep0_kernel(float* __restrict__ KVz,
                             const float* __restrict__ pw, unsigned short* __restrict__ wfrag,
                             const float* __restrict__ qw, unsigned short* __restrict__ wqkvf) {
    const int bid = blockIdx.x;
    if (bid < 81) {
        KVz[bid * 256 + threadIdx.x] = 0.f;   // 81*256 == 20736 exactly
    } else if (bid < 337) {
        const int idx = (bid - 81) * 256 + threadIdx.x;   // 0..65535
        const int kk = idx & 63;
        const int co = (idx >> 6) & 63;
        const int ks = idx >> 12;
        const int kg = ks * 64 + kk;
        const int ci = kg >> 4, tap = kg & 15;
        const float vv = (tap < 9) ? pw[(co * 64 + ci) * 9 + tap] : 0.f;
        const int kx = (((kk >> 3) ^ (co & 7)) << 3) | (kk & 7);
        wfrag[((size_t)ks * 64 + co) * 64 + kx] = f2h_bits(vv);
    } else {
        const int idx = (bid - 337) * 256 + threadIdx.x;  // 0..24575
        const int hl = idx / 12288;
        const int r  = idx - hl * 12288;
        const int sec = r >> 12;
        const int r2  = r & 4095;
        const int co  = r2 >> 6;
        const int ci  = r2 & 63;
        const float vv = qw[(sec * 64 + co) * 64 + ci];
        const _Float16 h = (_Float16)vv;
        const float out = hl ? (vv - (float)h) : vv;
        wqkvf[idx] = f2h_bits(out);   // layout [hl][sec][co][ci]
    }
}

// ---------------- Kernel A: qkv 1x1 conv; W frags from global regs; X staged once ----
// grid (128 pixblocks, B), block 256 = 4 waves (wave -> 32-pix strip).
// Per section: 16 W-frag loads (L2, once) -> 48 MFMA -> repack f16 -> uint4 stores.
__global__ void qkv_kernel(const float* __restrict__ x, const unsigned short* __restrict__ wqkvf,
                           const float* __restrict__ bias,
                           unsigned short* __restrict__ q, unsigned short* __restrict__ k,
                           unsigned short* __restrict__ v) {
    const int pix0 = blockIdx.x * 128;
    const int b    = blockIdx.y;
    const int tid  = threadIdx.x;
    const int lane = tid & 63;
    const int wv   = tid >> 6;

    __shared__ _Float16 xh[128][72], xl[128][72];   // 36864 B
    __shared__ unsigned short rep[64 * 128];        // 16384 B

    // ---- stage X once, float4 loads ----
    {
        const float* xb = x + (size_t)b * CC * LL + pix0;
        for (int i4 = tid; i4 < 2048; i4 += 256) {
            const int ci = i4 >> 5;
            const int px = (i4 & 31) * 4;
            const float4 vv = *(const float4*)&xb[(size_t)ci * LL + px];
            _Float16 h;
            h = (_Float16)vv.x; xh[px + 0][ci] = h; xl[px + 0][ci] = (_Float16)(vv.x - (float)h);
            h = (_Float16)vv.y; xh[px + 1][ci] = h; xl[px + 1][ci] = (_Float16)(vv.y - (float)h);
            h = (_Float16)vv.z; xh[px + 2][ci] = h; xl[px + 2][ci] = (_Float16)(vv.z - (float)h);
            h = (_Float16)vv.w; xh[px + 3][ci] = h; xl[px + 3][ci] = (_Float16)(vv.w - (float)h);
        }
    }
    __syncthreads();

    const int g8 = (lane >> 4) * 8;
    const int rl = lane & 15;

    for (int sec = 0; sec < 3; ++sec) {
        // ---- W fragments: per-lane global loads, once per section ----
        f16x8 ah[4][2], al[4][2];
#pragma unroll
        for (int ct = 0; ct < 4; ++ct)
#pragma unroll
            for (int ks = 0; ks < 2; ++ks) {
                const int off = sec * 4096 + (ct * 16 + rl) * 64 + ks * 32 + g8;
                ah[ct][ks] = *(const f16x8*)&wqkvf[off];
                al[ct][ks] = *(const f16x8*)&wqkvf[12288 + off];
            }

        f32x4 acc[4][2];
#pragma unroll
        for (int ct = 0; ct < 4; ++ct)
#pragma unroll
            for (int pt = 0; pt < 2; ++pt) acc[ct][pt] = (f32x4)0.f;

#pragma unroll
        for (int ks = 0; ks < 2; ++ks) {
            const int kb = ks * 32 + g8;
            f16x8 bh[2], bl[2];
#pragma unroll
            for (int pt = 0; pt < 2; ++pt) {
                bh[pt] = *(const f16x8*)&xh[wv * 32 + pt * 16 + rl][kb];
                bl[pt] = *(const f16x8*)&xl[wv * 32 + pt * 16 + rl][kb];
            }
#pragma unroll
            for (int ct = 0; ct < 4; ++ct)
#pragma unroll
                for (int pt = 0; pt < 2; ++pt) {
                    acc[ct][pt] = __builtin_amdgcn_mfma_f32_16x16x32_f16(ah[ct][ks], bh[pt], acc[ct][pt], 0, 0, 0);
                    acc[ct][pt] = __builtin_amdgcn_mfma_f32_16x16x32_f16(ah[ct][ks], bl[pt], acc[ct][pt], 0, 0, 0);
                    acc[ct][pt] = __builtin_amdgcn_mfma_f32_16x16x32_f16(al[ct][ks], bh[pt], acc[ct][pt], 0, 0, 0);
                }
        }

        __syncthreads();   // previous section's rep reads complete
        const bool do_relu = (sec < 2);
#pragma unroll
        for (int ct = 0; ct < 4; ++ct) {
            const int co_b = ct * 16 + (lane >> 4) * 4;
#pragma unroll
            for (int pt = 0; pt < 2; ++pt) {
                const int pxl = wv * 32 + pt * 16 + rl;
#pragma unroll
                for (int j = 0; j < 4; ++j) {
                    const int co = co_b + j;
                    float val = acc[ct][pt][j] + bias[sec * 64 + co];
                    if (do_relu) val = fmaxf(val, 0.f);
                    rep[co * 128 + pxl] = f2h_bits(val);
                }
            }
        }
        __syncthreads();

        unsigned short* dst = ((sec == 0) ? q : (sec == 1) ? k : v) + (size_t)b * 64 * LL;
#pragma unroll
        for (int i = 0; i < 4; ++i) {
            const int slot = i * 256 + tid;
            const int co = slot >> 4;
            const int u4 = slot & 15;
            *(uint4*)(dst + (size_t)co * LL + pix0 + u4 * 8) = *(const uint4*)&rep[co * 128 + u4 * 8];
        }
    }
}

// ---------------- Kernel B: KV/KS partials, f16 k/v, pixel-pair lanes, atomics ------
__global__ void kv_kernel(const unsigned short* __restrict__ k,
                          const unsigned short* __restrict__ v,
                          float* __restrict__ KV, float* __restrict__ KS) {
    const int chunk = blockIdx.x;
    const int h = blockIdx.y;
    const int b = blockIdx.z;
    const int tid = threadIdx.x;
    const int c  = tid >> 5;
    const int s  = tid & 31;
    const int half = s >> 4;
    const int sl   = s & 15;
    const int cpb  = half * 4;

    __shared__ float klds[8][6][130];

    {
        const unsigned short* kb = k + ((size_t)(b * 64) + 8 * h) * LL;
        for (int t = tid; t < 8 * 6 * 130; t += 256) {
            const int ch = t / 780;
            const int r1 = t - ch * 780;
            const int lr = r1 / 130;
            const int cx = r1 - lr * 130;
            const int gy = chunk * 4 + lr - 1;
            const int gx = cx - 1;
            const bool ok = (gy >= 0 && gy < HH && gx >= 0 && gx < WW);
            klds[ch][lr][cx] = ok ? h2f_u16(kb[(size_t)ch * LL + gy * WW + gx]) : 0.f;
        }
    }
    __syncthreads();

    const unsigned short* vbase = v + ((size_t)(b * 64) + 8 * h + cpb) * LL;

    float kv4[9][4] = {{0.f}};
    float ks[9] = {0.f};

    for (int r = 0; r < 4; ++r) {
        const int y = chunk * 4 + r;
        for (int g = 0; g < 4; ++g) {
            const int col0 = g * 32 + sl * 2;
            float va[4], vb2[4];
#pragma unroll
            for (int cp = 0; cp < 4; ++cp) {
                const unsigned int u = *(const unsigned int*)(vbase + (size_t)cp * LL + y * WW + col0);
                va[cp]  = h2f_lo(u);
                vb2[cp] = h2f_hi(u);
            }
            float kw[3][4];
#pragma unroll
            for (int dy = 0; dy < 3; ++dy)
#pragma unroll
                for (int dxx = 0; dxx < 4; ++dxx)
                    kw[dy][dxx] = klds[c][r + dy][col0 + dxx];
#pragma unroll
            for (int dy = 0; dy < 3; ++dy)
#pragma unroll
                for (int dx = 0; dx < 3; ++dx) {
                    const int p = dy * 3 + dx;
                    const float ka  = kw[dy][dx];
                    const float kb2 = kw[dy][dx + 1];
                    ks[p] += ka + kb2;
#pragma unroll
                    for (int cp = 0; cp < 4; ++cp)
                        kv4[p][cp] = fmaf(kb2, vb2[cp], fmaf(ka, va[cp], kv4[p][cp]));
                }
        }
    }

#pragma unroll
    for (int p = 0; p < 9; ++p) {
#pragma unroll
        for (int m = 8; m >= 1; m >>= 1) ks[p] += __shfl_xor(ks[p], m);
#pragma unroll
        for (int cp = 0; cp < 4; ++cp) {
#pragma unroll
            for (int m = 8; m >= 1; m >>= 1) kv4[p][cp] += __shfl_xor(kv4[p][cp], m);
        }
    }

    if (sl == 0) {
        const int bh = b * NH + h;
        float* kvb = KV + (size_t)bh * 576;
#pragma unroll
        for (int p = 0; p < 9; ++p) {
#pragma unroll
            for (int cp = 0; cp < 4; ++cp)
                atomicAdd(&kvb[(c * 9 + p) * 8 + cpb + cp], kv4[p][cp]);
            if (half == 0) atomicAdd(&KS[(size_t)bh * 72 + c * 9 + p], ks[p]);
        }
    }
}

// ---------------- Kernel C: attn, pixel-pair per thread, uint transport ----------
__global__ void attn_kernel(const unsigned short* __restrict__ q, const float* __restrict__ KV,
                            const float* __restrict__ KS, unsigned int* __restrict__ aofu) {
    const int y = blockIdx.x;
    const int h = blockIdx.y;
    const int b = blockIdx.z;
    const int t = threadIdx.x;   // 0..63

    float out0[8] = {0.f}, out1[8] = {0.f};
    float den0 = 0.f, den1 = 0.f;
    const int kvbase = (b * NH + h) * 8;
    const bool tlo = (t > 0), thi = (t < 63);

    for (int c = 0; c < 8; ++c) {
        const unsigned short* qc = q + ((size_t)(b * 64) + 8 * h + c) * LL;
        float qw[3][6];
#pragma unroll
        for (int dy = 0; dy < 3; ++dy) {
            const int yy = y + dy - 1;
            const bool yok = (yy >= 0 && yy < HH);
            const unsigned short* row = qc + yy * WW;
            const unsigned int u0 = (yok && tlo) ? *(const unsigned int*)(row + 2 * t - 2) : 0u;
            const unsigned int u1 = yok ? *(const unsigned int*)(row + 2 * t) : 0u;
            const unsigned int u2 = (yok && thi) ? *(const unsigned int*)(row + 2 * t + 2) : 0u;
            qw[dy][0] = h2f_lo(u0);  qw[dy][1] = h2f_hi(u0);
            qw[dy][2] = h2f_lo(u1);  qw[dy][3] = h2f_hi(u1);
            qw[dy][4] = h2f_lo(u2);  qw[dy][5] = h2f_hi(u2);
        }
        const float* kvr = KV + ((size_t)(kvbase + c) * 9) * 8;  // wave-uniform
        const float* ksr = KS + (size_t)(kvbase + c) * 9;
#pragma unroll
        for (int dy = 0; dy < 3; ++dy)
#pragma unroll
            for (int dx = 0; dx < 3; ++dx) {
                const int p = dy * 3 + dx;
                const float q0 = qw[dy][1 + dx];
                const float q1 = qw[dy][2 + dx];
                const float ksv = ksr[p];
                den0 = fmaf(q0, ksv, den0);
                den1 = fmaf(q1, ksv, den1);
#pragma unroll
                for (int cp = 0; cp < 8; ++cp) {
                    const float kvv = kvr[p * 8 + cp];
                    out0[cp] = fmaf(q0, kvv, out0[cp]);
                    out1[cp] = fmaf(q1, kvv, out1[cp]);
                }
            }
    }
    const float inv0 = 1.f / (den0 + EPSF);
    const float inv1 = 1.f / (den1 + EPSF);
    const int pixu = y * (WW / 2) + t;
#pragma unroll
    for (int cp = 0; cp < 8; ++cp) {
        const unsigned int lo = f2h_bits(out0[cp] * inv0);
        const unsigned int hi = f2h_bits(out1[cp] * inv1);
        aofu[((size_t)(b * 64) + h * 8 + cp) * (LL / 2) + pixu] = lo | (hi << 16);
    }
}

// ---------------- Kernel D: 3x3 conv via MFMA; pair-staged P (uint loads) ----------
#define CONV_PREFETCH(KS)                                                        \
    do {                                                                         \
        if (tid < 128) {                                                         \
            const unsigned short* src_ = aofb + (size_t)((KS) * 4 + scis) * LL;  \
            pa0 = (oky0 && u0ok) ? *(const unsigned int*)(src_ + o_m - 2) : 0u;  \
            pa1 = oky0 ? *(const unsigned int*)(src_ + o_m) : 0u;                \
            pa2 = (oky0 && u2ok) ? *(const unsigned int*)(src_ + o_m + 2) : 0u;  \
            pb0 = u0ok ? *(const unsigned int*)(src_ + o_c - 2) : 0u;            \
            pb1 = *(const unsigned int*)(src_ + o_c);                            \
            pb2 = u2ok ? *(const unsigned int*)(src_ + o_c + 2) : 0u;            \
            pc0 = (oky2 && u0ok) ? *(const unsigned int*)(src_ + o_p - 2) : 0u;  \
            pc1 = oky2 ? *(const unsigned int*)(src_ + o_p) : 0u;                \
            pc2 = (oky2 && u2ok) ? *(const unsigned int*)(src_ + o_p + 2) : 0u;  \
        } else {                                                                 \
            const uint4* wsrc_ = (const uint4*)(wfrag + (size_t)(KS) * 4096);    \
            wf0 = wsrc_[wt];        wf1 = wsrc_[128 + wt];                       \
            wf2 = wsrc_[256 + wt];  wf3 = wsrc_[384 + wt];                       \
        }                                                                        \
    } while (0)

__global__ __launch_bounds__(256) void conv_kernel(const unsigned short* __restrict__ aof,
                                                   const unsigned short* __restrict__ wfrag,
                                                   const float* __restrict__ bias,
                                                   float* __restrict__ out) {
    const int bid = blockIdx.x;
    const int swz = (bid & 7) * 128 + (bid >> 3);   // XCD-chunked
    const int b = swz >> 8;
    const int rem = swz & 255;
    const int y = rem >> 1;
    const int colbase = (rem & 1) * 64;
    const int tid = threadIdx.x;
    const int lane = tid & 63;
    const int wv = tid >> 6;
    const int rl = lane & 15;
    const int g  = lane >> 4;

    __shared__ unsigned short plds[2][64 * 64];
    __shared__ unsigned short wlds[2][64 * 64];

    f32x4 acc[4];
#pragma unroll
    for (int ct = 0; ct < 4; ++ct) acc[ct] = (f32x4)0.f;

    const int pair = tid & 31;
    const int scis = (tid >> 5) & 3;
    const int wt   = tid & 127;
    const int pxA  = pair * 2;
    const int pxB  = pxA + 1;

    const unsigned short* aofb = aof + (size_t)b * 64 * LL;
    const int xc0 = colbase + pxA;
    const int o_c = y * WW + xc0;
    const int o_m = o_c - WW;
    const int o_p = o_c + WW;
    const bool oky0 = (y > 0);
    const bool oky2 = (y < HH - 1);
    const bool u0ok = (xc0 >= 2);
    const bool u2ok = (xc0 + 3 < WW);
    const int xsA0 = (((2 * scis)     ^ (pxA & 7)) << 3);
    const int xsA1 = (((2 * scis + 1) ^ (pxA & 7)) << 3);
    const int xsB0 = (((2 * scis)     ^ (pxB & 7)) << 3);
    const int xsB1 = (((2 * scis + 1) ^ (pxB & 7)) << 3);

    unsigned int pa0, pa1, pa2, pb0, pb1, pb2, pc0, pc1, pc2;
    uint4 wf0, wf1, wf2, wf3;

    CONV_PREFETCH(0);

    for (int ks = 0; ks < 16; ++ks) {
        const int cur = ks & 1;
        if (tid < 128) {
            unsigned short ha[16], hb[16];
            ha[0] = (unsigned short)(pa0 >> 16);      ha[1] = (unsigned short)(pa1 & 0xffffu);  ha[2] = (unsigned short)(pa1 >> 16);
            ha[3] = (unsigned short)(pb0 >> 16);      ha[4] = (unsigned short)(pb1 & 0xffffu);  ha[5] = (unsigned short)(pb1 >> 16);
            ha[6] = (unsigned short)(pc0 >> 16);      ha[7] = (unsigned short)(pc1 & 0xffffu);  ha[8] = (unsigned short)(pc1 >> 16);
            hb[0] = (unsigned short)(pa1 & 0xffffu);  hb[1] = (unsigned short)(pa1 >> 16);      hb[2] = (unsigned short)(pa2 & 0xffffu);
            hb[3] = (unsigned short)(pb1 & 0xffffu);  hb[4] = (unsigned short)(pb1 >> 16);      hb[5] = (unsigned short)(pb2 & 0xffffu);
            hb[6] = (unsigned short)(pc1 & 0xffffu);  hb[7] = (unsigned short)(pc1 >> 16);      hb[8] = (unsigned short)(pc2 & 0xffffu);
#pragma unroll
            for (int j = 9; j < 16; ++j) { ha[j] = 0; hb[j] = 0; }
            *(u16x8*)&plds[cur][pxA * 64 + xsA0] = *(u16x8*)&ha[0];
            *(u16x8*)&plds[cur][pxA * 64 + xsA1] = *(u16x8*)&ha[8];
            *(u16x8*)&plds[cur][pxB * 64 + xsB0] = *(u16x8*)&hb[0];
            *(u16x8*)&plds[cur][pxB * 64 + xsB1] = *(u16x8*)&hb[8];
        } else {
            uint4* wdst = (uint4*)&wlds[cur][0];
            wdst[wt]        = wf0;
            wdst[128 + wt]  = wf1;
            wdst[256 + wt]  = wf2;
            wdst[384 + wt]  = wf3;
        }
        __syncthreads();
        if (ks < 15) CONV_PREFETCH(ks + 1);

#pragma unroll
        for (int ksub = 0; ksub < 2; ++ksub) {
            const int xs = (((ksub * 4 + g) ^ (rl & 7)) << 3);
            const int row = wv * 16 + rl;
            const f16x8 bh = *(const f16x8*)&plds[cur][row * 64 + xs];
#pragma unroll
            for (int ct = 0; ct < 4; ++ct) {
                const int rowa = ct * 16 + rl;
                const f16x8 ah = *(const f16x8*)&wlds[cur][rowa * 64 + xs];
                acc[ct] = __builtin_amdgcn_mfma_f32_16x16x32_f16(ah, bh, acc[ct], 0, 0, 0);
            }
        }
    }

#pragma unroll
    for (int ct = 0; ct < 4; ++ct) {
        const int co_b = ct * 16 + g * 4;
        const int px = colbase + wv * 16 + rl;
#pragma unroll
        for (int j = 0; j < 4; ++j) {
            const int co = co_b + j;
            out[((size_t)b * 64 + co) * LL + y * WW + px] = acc[ct][j] + bias[co];
        }
    }
}

extern "C" void kernel_launch(void* const* d_in, const int* in_sizes, int n_in,
                              void* d_out, int out_size, void* d_ws, size_t ws_size,
                              hipStream_t stream) {
    const float* x      = (const float*)d_in[0];
    const float* qkv_w  = (const float*)d_in[1];
    const float* qkv_b  = (const float*)d_in[2];
    const float* proj_w = (const float*)d_in[3];
    const float* proj_b = (const float*)d_in[4];
    float* out = (float*)d_out;
    float* ws  = (float*)d_ws;

    const size_t n1 = (size_t)4 * 64 * LL;      // one B*C*L fp32 plane set
    unsigned short* qb  = (unsigned short*)ws;            // f16
    unsigned short* kb  = (unsigned short*)(ws + n1);     // f16
    unsigned short* vb  = (unsigned short*)(ws + 2 * n1); // f16
    unsigned short* aof = (unsigned short*)(ws + 3 * n1); // f16
    float* KV   = ws + 4 * n1;                  // 18432 floats (+ KS 2304, contiguous)
    float* KS   = KV + 18432;
    unsigned short* wfrag  = (unsigned short*)(KS + 2304);     // 65536 halfs
    unsigned short* wqkvf  = wfrag + 65536;                    // 24576 halfs

    prep0_kernel<<<433, 256, 0, stream>>>(KV, proj_w, wfrag, qkv_w, wqkvf);
    qkv_kernel<<<dim3(128, 4), 256, 0, stream>>>(x, wqkvf, qkv_b, qb, kb, vb);
    kv_kernel<<<dim3(KVCHUNKS, NH, 4), 256, 0, stream>>>(kb, vb, KV, KS);
    attn_kernel<<<dim3(128, NH, 4), 64, 0, stream>>>(qb, KV, KS, (unsigned int*)aof);
    conv_kernel<<<1024, 256, 0, stream>>>(aof, wfrag, proj_b, out);
}

// Round 24
// 106.955 us; speedup vs baseline: 1.1676x; 1.1676x over previous
//
#include <hip/hip_runtime.h>
#include <hip/hip_fp16.h>

#define LL 16384
#define HH 128
#define WW 128
#define CC 64
#define NH 8
#define EPSF 1e-7f
#define KVCHUNKS 32

typedef __attribute__((ext_vector_type(8))) _Float16 f16x8;
typedef __attribute__((ext_vector_type(4))) float f32x4;
typedef __attribute__((ext_vector_type(8))) unsigned short u16x8;

static __device__ __forceinline__ unsigned short f2h_bits(float v) {
    const _Float16 h = (_Float16)v;
    unsigned short b;
    __builtin_memcpy(&b, &h, 2);
    return b;
}
static __device__ __forceinline__ float h2f_u16(unsigned short s) {
    _Float16 h;
    __builtin_memcpy(&h, &s, 2);
    return (float)h;
}
static __device__ __forceinline__ float h2f_lo(unsigned int u) {
    return h2f_u16((unsigned short)(u & 0xffffu));
}
static __device__ __forceinline__ float h2f_hi(unsigned int u) {
    return h2f_u16((unsigned short)(u >> 16));
}

// ---------------- Kernel P0: conv wprep + qkv wprep (no deps) ----------
// blocks 0-255: conv wfrag; 256-351: qkv wqkvf.
__global__ void prep0_kernel(const float* __restrict__ pw, unsigned short* __restrict__ wfrag,
                             const float* __restrict__ qw, unsigned short* __restrict__ wqkvf) {
    const int bid = blockIdx.x;
    if (bid < 256) {
        const int idx = bid * 256 + threadIdx.x;   // 0..65535
        const int kk = idx & 63;
        const int co = (idx >> 6) & 63;
        const int ks = idx >> 12;
        const int kg = ks * 64 + kk;
        const int ci = kg >> 4, tap = kg & 15;
        const float vv = (tap < 9) ? pw[(co * 64 + ci) * 9 + tap] : 0.f;
        const int kx = (((kk >> 3) ^ (co & 7)) << 3) | (kk & 7);
        wfrag[((size_t)ks * 64 + co) * 64 + kx] = f2h_bits(vv);
    } else {
        const int idx = (bid - 256) * 256 + threadIdx.x;  // 0..24575
        const int hl = idx / 12288;
        const int r  = idx - hl * 12288;
        const int sec = r >> 12;
        const int r2  = r & 4095;
        const int co  = r2 >> 6;
        const int ci  = r2 & 63;
        const float vv = qw[(sec * 64 + co) * 64 + ci];
        const _Float16 h = (_Float16)vv;
        const float out = hl ? (vv - (float)h) : vv;
        wqkvf[idx] = f2h_bits(out);   // layout [hl][sec][co][ci]
    }
}

// ---------------- Kernel A: qkv 1x1 conv; W frags from global regs; X staged once ----
__global__ void qkv_kernel(const float* __restrict__ x, const unsigned short* __restrict__ wqkvf,
                           const float* __restrict__ bias,
                           unsigned short* __restrict__ q, unsigned short* __restrict__ k,
                           unsigned short* __restrict__ v) {
    const int pix0 = blockIdx.x * 128;
    const int b    = blockIdx.y;
    const int tid  = threadIdx.x;
    const int lane = tid & 63;
    const int wv   = tid >> 6;

    __shared__ _Float16 xh[128][72], xl[128][72];   // 36864 B
    __shared__ unsigned short rep[64 * 128];        // 16384 B

    {
        const float* xb = x + (size_t)b * CC * LL + pix0;
        for (int i4 = tid; i4 < 2048; i4 += 256) {
            const int ci = i4 >> 5;
            const int px = (i4 & 31) * 4;
            const float4 vv = *(const float4*)&xb[(size_t)ci * LL + px];
            _Float16 h;
            h = (_Float16)vv.x; xh[px + 0][ci] = h; xl[px + 0][ci] = (_Float16)(vv.x - (float)h);
            h = (_Float16)vv.y; xh[px + 1][ci] = h; xl[px + 1][ci] = (_Float16)(vv.y - (float)h);
            h = (_Float16)vv.z; xh[px + 2][ci] = h; xl[px + 2][ci] = (_Float16)(vv.z - (float)h);
            h = (_Float16)vv.w; xh[px + 3][ci] = h; xl[px + 3][ci] = (_Float16)(vv.w - (float)h);
        }
    }
    __syncthreads();

    const int g8 = (lane >> 4) * 8;
    const int rl = lane & 15;

    for (int sec = 0; sec < 3; ++sec) {
        f16x8 ah[4][2], al[4][2];
#pragma unroll
        for (int ct = 0; ct < 4; ++ct)
#pragma unroll
            for (int ks = 0; ks < 2; ++ks) {
                const int off = sec * 4096 + (ct * 16 + rl) * 64 + ks * 32 + g8;
                ah[ct][ks] = *(const f16x8*)&wqkvf[off];
                al[ct][ks] = *(const f16x8*)&wqkvf[12288 + off];
            }

        f32x4 acc[4][2];
#pragma unroll
        for (int ct = 0; ct < 4; ++ct)
#pragma unroll
            for (int pt = 0; pt < 2; ++pt) acc[ct][pt] = (f32x4)0.f;

#pragma unroll
        for (int ks = 0; ks < 2; ++ks) {
            const int kb = ks * 32 + g8;
            f16x8 bh[2], bl[2];
#pragma unroll
            for (int pt = 0; pt < 2; ++pt) {
                bh[pt] = *(const f16x8*)&xh[wv * 32 + pt * 16 + rl][kb];
                bl[pt] = *(const f16x8*)&xl[wv * 32 + pt * 16 + rl][kb];
            }
#pragma unroll
            for (int ct = 0; ct < 4; ++ct)
#pragma unroll
                for (int pt = 0; pt < 2; ++pt) {
                    acc[ct][pt] = __builtin_amdgcn_mfma_f32_16x16x32_f16(ah[ct][ks], bh[pt], acc[ct][pt], 0, 0, 0);
                    acc[ct][pt] = __builtin_amdgcn_mfma_f32_16x16x32_f16(ah[ct][ks], bl[pt], acc[ct][pt], 0, 0, 0);
                    acc[ct][pt] = __builtin_amdgcn_mfma_f32_16x16x32_f16(al[ct][ks], bh[pt], acc[ct][pt], 0, 0, 0);
                }
        }

        __syncthreads();
        const bool do_relu = (sec < 2);
#pragma unroll
        for (int ct = 0; ct < 4; ++ct) {
            const int co_b = ct * 16 + (lane >> 4) * 4;
#pragma unroll
            for (int pt = 0; pt < 2; ++pt) {
                const int pxl = wv * 32 + pt * 16 + rl;
#pragma unroll
                for (int j = 0; j < 4; ++j) {
                    const int co = co_b + j;
                    float val = acc[ct][pt][j] + bias[sec * 64 + co];
                    if (do_relu) val = fmaxf(val, 0.f);
                    rep[co * 128 + pxl] = f2h_bits(val);
                }
            }
        }
        __syncthreads();

        unsigned short* dst = ((sec == 0) ? q : (sec == 1) ? k : v) + (size_t)b * 64 * LL;
#pragma unroll
        for (int i = 0; i < 4; ++i) {
            const int slot = i * 256 + tid;
            const int co = slot >> 4;
            const int u4 = slot & 15;
            *(uint4*)(dst + (size_t)co * LL + pix0 + u4 * 8) = *(const uint4*)&rep[co * 128 + u4 * 8];
        }
    }
}

// ---------------- Kernel B: KV/KS partials -> KVp (deterministic, no atomics) -------
__global__ void kv_kernel(const unsigned short* __restrict__ k,
                          const unsigned short* __restrict__ v,
                          float* __restrict__ KVp) {
    const int chunk = blockIdx.x;
    const int h = blockIdx.y;
    const int b = blockIdx.z;
    const int tid = threadIdx.x;
    const int c  = tid >> 5;
    const int s  = tid & 31;
    const int half = s >> 4;
    const int sl   = s & 15;
    const int cpb  = half * 4;

    __shared__ float klds[8][6][130];

    {
        const unsigned short* kb = k + ((size_t)(b * 64) + 8 * h) * LL;
        for (int t = tid; t < 8 * 6 * 130; t += 256) {
            const int ch = t / 780;
            const int r1 = t - ch * 780;
            const int lr = r1 / 130;
            const int cx = r1 - lr * 130;
            const int gy = chunk * 4 + lr - 1;
            const int gx = cx - 1;
            const bool ok = (gy >= 0 && gy < HH && gx >= 0 && gx < WW);
            klds[ch][lr][cx] = ok ? h2f_u16(kb[(size_t)ch * LL + gy * WW + gx]) : 0.f;
        }
    }
    __syncthreads();

    const unsigned short* vbase = v + ((size_t)(b * 64) + 8 * h + cpb) * LL;

    float kv4[9][4] = {{0.f}};
    float ks[9] = {0.f};

    for (int r = 0; r < 4; ++r) {
        const int y = chunk * 4 + r;
        for (int g = 0; g < 4; ++g) {
            const int col0 = g * 32 + sl * 2;
            float va[4], vb2[4];
#pragma unroll
            for (int cp = 0; cp < 4; ++cp) {
                const unsigned int u = *(const unsigned int*)(vbase + (size_t)cp * LL + y * WW + col0);
                va[cp]  = h2f_lo(u);
                vb2[cp] = h2f_hi(u);
            }
            float kw[3][4];
#pragma unroll
            for (int dy = 0; dy < 3; ++dy)
#pragma unroll
                for (int dxx = 0; dxx < 4; ++dxx)
                    kw[dy][dxx] = klds[c][r + dy][col0 + dxx];
#pragma unroll
            for (int dy = 0; dy < 3; ++dy)
#pragma unroll
                for (int dx = 0; dx < 3; ++dx) {
                    const int p = dy * 3 + dx;
                    const float ka  = kw[dy][dx];
                    const float kb2 = kw[dy][dx + 1];
                    ks[p] += ka + kb2;
#pragma unroll
                    for (int cp = 0; cp < 4; ++cp)
                        kv4[p][cp] = fmaf(kb2, vb2[cp], fmaf(ka, va[cp], kv4[p][cp]));
                }
        }
    }

#pragma unroll
    for (int p = 0; p < 9; ++p) {
#pragma unroll
        for (int m = 8; m >= 1; m >>= 1) ks[p] += __shfl_xor(ks[p], m);
#pragma unroll
        for (int cp = 0; cp < 4; ++cp) {
#pragma unroll
            for (int m = 8; m >= 1; m >>= 1) kv4[p][cp] += __shfl_xor(kv4[p][cp], m);
        }
    }

    if (sl == 0) {
        float* dst = KVp + (((size_t)(b * NH + h) * KVCHUNKS) + chunk) * 648;
#pragma unroll
        for (int p = 0; p < 9; ++p) {
#pragma unroll
            for (int cp = 0; cp < 4; ++cp)
                dst[(c * 9 + p) * 8 + cpb + cp] = kv4[p][cp];
            if (half == 0) dst[576 + c * 9 + p] = ks[p];
        }
    }
}

// ---------------- Kernel B2: reduce 32 chunk-partials -> KV, KS ----------------
__global__ void kv_finalize(const float* __restrict__ KVp,
                            float* __restrict__ KV, float* __restrict__ KS) {
    const int bh = blockIdx.x;
    const float* src = KVp + (size_t)bh * KVCHUNKS * 648;
    for (int idx = threadIdx.x; idx < 648; idx += 256) {
        float s0 = 0.f, s1 = 0.f, s2 = 0.f, s3 = 0.f;
#pragma unroll
        for (int ch = 0; ch < KVCHUNKS; ch += 4) {
            s0 += src[(ch + 0) * 648 + idx];
            s1 += src[(ch + 1) * 648 + idx];
            s2 += src[(ch + 2) * 648 + idx];
            s3 += src[(ch + 3) * 648 + idx];
        }
        const float sum = (s0 + s1) + (s2 + s3);
        if (idx < 576) KV[(size_t)bh * 576 + idx] = sum;
        else           KS[(size_t)bh * 72 + (idx - 576)] = sum;
    }
}

// ---------------- Kernel C: attn, pixel-pair per thread, uint transport ----------
__global__ void attn_kernel(const unsigned short* __restrict__ q, const float* __restrict__ KV,
                            const float* __restrict__ KS, unsigned int* __restrict__ aofu) {
    const int y = blockIdx.x;
    const int h = blockIdx.y;
    const int b = blockIdx.z;
    const int t = threadIdx.x;   // 0..63

    float out0[8] = {0.f}, out1[8] = {0.f};
    float den0 = 0.f, den1 = 0.f;
    const int kvbase = (b * NH + h) * 8;
    const bool tlo = (t > 0), thi = (t < 63);

    for (int c = 0; c < 8; ++c) {
        const unsigned short* qc = q + ((size_t)(b * 64) + 8 * h + c) * LL;
        float qw[3][6];
#pragma unroll
        for (int dy = 0; dy < 3; ++dy) {
            const int yy = y + dy - 1;
            const bool yok = (yy >= 0 && yy < HH);
            const unsigned short* row = qc + yy * WW;
            const unsigned int u0 = (yok && tlo) ? *(const unsigned int*)(row + 2 * t - 2) : 0u;
            const unsigned int u1 = yok ? *(const unsigned int*)(row + 2 * t) : 0u;
            const unsigned int u2 = (yok && thi) ? *(const unsigned int*)(row + 2 * t + 2) : 0u;
            qw[dy][0] = h2f_lo(u0);  qw[dy][1] = h2f_hi(u0);
            qw[dy][2] = h2f_lo(u1);  qw[dy][3] = h2f_hi(u1);
            qw[dy][4] = h2f_lo(u2);  qw[dy][5] = h2f_hi(u2);
        }
        const float* kvr = KV + ((size_t)(kvbase + c) * 9) * 8;  // wave-uniform
        const float* ksr = KS + (size_t)(kvbase + c) * 9;
#pragma unroll
        for (int dy = 0; dy < 3; ++dy)
#pragma unroll
            for (int dx = 0; dx < 3; ++dx) {
                const int p = dy * 3 + dx;
                const float q0 = qw[dy][1 + dx];
                const float q1 = qw[dy][2 + dx];
                const float ksv = ksr[p];
                den0 = fmaf(q0, ksv, den0);
                den1 = fmaf(q1, ksv, den1);
#pragma unroll
                for (int cp = 0; cp < 8; ++cp) {
                    const float kvv = kvr[p * 8 + cp];
                    out0[cp] = fmaf(q0, kvv, out0[cp]);
                    out1[cp] = fmaf(q1, kvv, out1[cp]);
                }
            }
    }
    const float inv0 = 1.f / (den0 + EPSF);
    const float inv1 = 1.f / (den1 + EPSF);
    const int pixu = y * (WW / 2) + t;
#pragma unroll
    for (int cp = 0; cp < 8; ++cp) {
        const unsigned int lo = f2h_bits(out0[cp] * inv0);
        const unsigned int hi = f2h_bits(out1[cp] * inv1);
        aofu[((size_t)(b * 64) + h * 8 + cp) * (LL / 2) + pixu] = lo | (hi << 16);
    }
}

// ---------------- Kernel D: 3x3 conv via MFMA; pair-staged P (uint loads) ----------
#define CONV_PREFETCH(KS)                                                        \
    do {                                                                         \
        if (tid < 128) {                                                         \
            const unsigned short* src_ = aofb + (size_t)((KS) * 4 + scis) * LL;  \
            pa0 = (oky0 && u0ok) ? *(const unsigned int*)(src_ + o_m - 2) : 0u;  \
            pa1 = oky0 ? *(const unsigned int*)(src_ + o_m) : 0u;                \
            pa2 = (oky0 && u2ok) ? *(const unsigned int*)(src_ + o_m + 2) : 0u;  \
            pb0 = u0ok ? *(const unsigned int*)(src_ + o_c - 2) : 0u;            \
            pb1 = *(const unsigned int*)(src_ + o_c);                            \
            pb2 = u2ok ? *(const unsigned int*)(src_ + o_c + 2) : 0u;            \
            pc0 = (oky2 && u0ok) ? *(const unsigned int*)(src_ + o_p - 2) : 0u;  \
            pc1 = oky2 ? *(const unsigned int*)(src_ + o_p) : 0u;                \
            pc2 = (oky2 && u2ok) ? *(const unsigned int*)(src_ + o_p + 2) : 0u;  \
        } else {                                                                 \
            const uint4* wsrc_ = (const uint4*)(wfrag + (size_t)(KS) * 4096);    \
            wf0 = wsrc_[wt];        wf1 = wsrc_[128 + wt];                       \
            wf2 = wsrc_[256 + wt];  wf3 = wsrc_[384 + wt];                       \
        }                                                                        \
    } while (0)

__global__ __launch_bounds__(256) void conv_kernel(const unsigned short* __restrict__ aof,
                                                   const unsigned short* __restrict__ wfrag,
                                                   const float* __restrict__ bias,
                                                   float* __restrict__ out) {
    const int bid = blockIdx.x;
    const int swz = (bid & 7) * 128 + (bid >> 3);   // XCD-chunked
    const int b = swz >> 8;
    const int rem = swz & 255;
    const int y = rem >> 1;
    const int colbase = (rem & 1) * 64;
    const int tid = threadIdx.x;
    const int lane = tid & 63;
    const int wv = tid >> 6;
    const int rl = lane & 15;
    const int g  = lane >> 4;

    __shared__ unsigned short plds[2][64 * 64];
    __shared__ unsigned short wlds[2][64 * 64];

    f32x4 acc[4];
#pragma unroll
    for (int ct = 0; ct < 4; ++ct) acc[ct] = (f32x4)0.f;

    const int pair = tid & 31;
    const int scis = (tid >> 5) & 3;
    const int wt   = tid & 127;
    const int pxA  = pair * 2;
    const int pxB  = pxA + 1;

    const unsigned short* aofb = aof + (size_t)b * 64 * LL;
    const int xc0 = colbase + pxA;
    const int o_c = y * WW + xc0;
    const int o_m = o_c - WW;
    const int o_p = o_c + WW;
    const bool oky0 = (y > 0);
    const bool oky2 = (y < HH - 1);
    const bool u0ok = (xc0 >= 2);
    const bool u2ok = (xc0 + 3 < WW);
    const int xsA0 = (((2 * scis)     ^ (pxA & 7)) << 3);
    const int xsA1 = (((2 * scis + 1) ^ (pxA & 7)) << 3);
    const int xsB0 = (((2 * scis)     ^ (pxB & 7)) << 3);
    const int xsB1 = (((2 * scis + 1) ^ (pxB & 7)) << 3);

    unsigned int pa0, pa1, pa2, pb0, pb1, pb2, pc0, pc1, pc2;
    uint4 wf0, wf1, wf2, wf3;

    CONV_PREFETCH(0);

    for (int ks = 0; ks < 16; ++ks) {
        const int cur = ks & 1;
        if (tid < 128) {
            unsigned short ha[16], hb[16];
            ha[0] = (unsigned short)(pa0 >> 16);      ha[1] = (unsigned short)(pa1 & 0xffffu);  ha[2] = (unsigned short)(pa1 >> 16);
            ha[3] = (unsigned short)(pb0 >> 16);      ha[4] = (unsigned short)(pb1 & 0xffffu);  ha[5] = (unsigned short)(pb1 >> 16);
            ha[6] = (unsigned short)(pc0 >> 16);      ha[7] = (unsigned short)(pc1 & 0xffffu);  ha[8] = (unsigned short)(pc1 >> 16);
            hb[0] = (unsigned short)(pa1 & 0xffffu);  hb[1] = (unsigned short)(pa1 >> 16);      hb[2] = (unsigned short)(pa2 & 0xffffu);
            hb[3] = (unsigned short)(pb1 & 0xffffu);  hb[4] = (unsigned short)(pb1 >> 16);      hb[5] = (unsigned short)(pb2 & 0xffffu);
            hb[6] = (unsigned short)(pc1 & 0xffffu);  hb[7] = (unsigned short)(pc1 >> 16);      hb[8] = (unsigned short)(pc2 & 0xffffu);
#pragma unroll
            for (int j = 9; j < 16; ++j) { ha[j] = 0; hb[j] = 0; }
            *(u16x8*)&plds[cur][pxA * 64 + xsA0] = *(u16x8*)&ha[0];
            *(u16x8*)&plds[cur][pxA * 64 + xsA1] = *(u16x8*)&ha[8];
            *(u16x8*)&plds[cur][pxB * 64 + xsB0] = *(u16x8*)&hb[0];
            *(u16x8*)&plds[cur][pxB * 64 + xsB1] = *(u16x8*)&hb[8];
        } else {
            uint4* wdst = (uint4*)&wlds[cur][0];
            wdst[wt]        = wf0;
            wdst[128 + wt]  = wf1;
            wdst[256 + wt]  = wf2;
            wdst[384 + wt]  = wf3;
        }
        __syncthreads();
        if (ks < 15) CONV_PREFETCH(ks + 1);

#pragma unroll
        for (int ksub = 0; ksub < 2; ++ksub) {
            const int xs = (((ksub * 4 + g) ^ (rl & 7)) << 3);
            const int row = wv * 16 + rl;
            const f16x8 bh = *(const f16x8*)&plds[cur][row * 64 + xs];
#pragma unroll
            for (int ct = 0; ct < 4; ++ct) {
                const int rowa = ct * 16 + rl;
                const f16x8 ah = *(const f16x8*)&wlds[cur][rowa * 64 + xs];
                acc[ct] = __builtin_amdgcn_mfma_f32_16x16x32_f16(ah, bh, acc[ct], 0, 0, 0);
            }
        }
    }

#pragma unroll
    for (int ct = 0; ct < 4; ++ct) {
        const int co_b = ct * 16 + g * 4;
        const int px = colbase + wv * 16 + rl;
#pragma unroll
        for (int j = 0; j < 4; ++j) {
            const int co = co_b + j;
            out[((size_t)b * 64 + co) * LL + y * WW + px] = acc[ct][j] + bias[co];
        }
    }
}

extern "C" void kernel_launch(void* const* d_in, const int* in_sizes, int n_in,
                              void* d_out, int out_size, void* d_ws, size_t ws_size,
                              hipStream_t stream) {
    const float* x      = (const float*)d_in[0];
    const float* qkv_w  = (const float*)d_in[1];
    const float* qkv_b  = (const float*)d_in[2];
    const float* proj_w = (const float*)d_in[3];
    const float* proj_b = (const float*)d_in[4];
    float* out = (float*)d_out;
    float* ws  = (float*)d_ws;

    const size_t n1 = (size_t)4 * 64 * LL;      // one B*C*L fp32 plane set
    unsigned short* qb  = (unsigned short*)ws;            // f16
    unsigned short* kb  = (unsigned short*)(ws + n1);     // f16
    unsigned short* vb  = (unsigned short*)(ws + 2 * n1); // f16
    unsigned short* aof = (unsigned short*)(ws + 3 * n1); // f16
    float* KV   = ws + 4 * n1;                  // 18432 floats
    float* KS   = KV + 18432;                   // 2304 floats
    float* KVp  = KS + 2304;                    // 32*32*648 = 663552 floats
    unsigned short* wfrag = (unsigned short*)(KVp + (size_t)32 * KVCHUNKS * 648);  // 65536 halfs
    unsigned short* wqkvf = wfrag + 65536;                                          // 24576 halfs

    prep0_kernel<<<352, 256, 0, stream>>>(proj_w, wfrag, qkv_w, wqkvf);
    qkv_kernel<<<dim3(128, 4), 256, 0, stream>>>(x, wqkvf, qkv_b, qb, kb, vb);
    kv_kernel<<<dim3(KVCHUNKS, NH, 4), 256, 0, stream>>>(kb, vb, KVp);
    kv_finalize<<<32, 256, 0, stream>>>(KVp, KV, KS);
    attn_kernel<<<dim3(128, NH, 4), 64, 0, stream>>>(qb, KV, KS, (unsigned int*)aof);
    conv_kernel<<<1024, 256, 0, stream>>>(aof, wfrag, proj_b, out);
}